// Round 5
// baseline (1362.994 us; speedup 1.0000x reference)
//
#include <hip/hip_runtime.h>

// ---------------- problem constants ----------------
#define NN      8192            // nodes
#define BB      32              // batch
#define EE      262144          // edges per support (2^18)
#define NB      (NN*BB)         // 262144 gemm rows
#define NS      2               // supports

// ---------------- workspace layout (byte offsets) ----------------
// outacc  f32  [NN][BB][64]   64 MB @ 0
// zs      bf16 [NN][BB][128]  64 MB @ 64MB      (slot0 | slot1 per b)
// tbuf    bf16 [NN][BB][64]   32 MB @ 128MB
#define BOFF_OUTACC 0
#define BOFF_ZS     67108864
#define BOFF_T      134217728
#define BOFF_CSRVAL 167772160                    // f32  NS*EE
#define BOFF_CSRCOL (BOFF_CSRVAL + 2097152)      // int  NS*EE
#define BOFF_ROWPTR (BOFF_CSRCOL + 2097152)      // int  NS*(NN+1)
#define BOFF_CURSOR (BOFF_ROWPTR + 65544)        // int  NS*NN
#define BOFF_COUNTS (BOFF_CURSOR + 65536)        // int  NS*NN

// ---------------- bf16 helpers (RNE) ----------------
__device__ __forceinline__ unsigned short f2bf(float f) {
    union { float f; unsigned u; } v; v.f = f;
    unsigned r = v.u + 0x7fffu + ((v.u >> 16) & 1u);
    return (unsigned short)(r >> 16);
}
__device__ __forceinline__ float bf_lo(unsigned u) {   // elem 0 (low 16 bits)
    union { unsigned u; float f; } v; v.u = u << 16; return v.f;
}
__device__ __forceinline__ float bf_hi(unsigned u) {   // elem 1 (high 16 bits)
    union { unsigned u; float f; } v; v.u = u & 0xffff0000u; return v.f;
}
__device__ __forceinline__ unsigned packbf(float lo, float hi) {
    return (unsigned)f2bf(lo) | ((unsigned)f2bf(hi) << 16);
}

// ---------------- CSR build ----------------
__global__ __launch_bounds__(256) void hist_kernel(const int* __restrict__ rows,
                                                   int* __restrict__ counts) {
    int idx = blockIdx.x * 256 + threadIdx.x;
    if (idx < NS * EE) {
        int s = idx >> 18;                 // EE = 2^18
        int r = rows[idx];
        atomicAdd(&counts[(s << 13) + r], 1);
    }
}

__global__ __launch_bounds__(1024) void scan_kernel(const int* __restrict__ counts,
                                                    int* __restrict__ row_ptr,
                                                    int* __restrict__ cursor) {
    const int s = blockIdx.x;
    const int tid = threadIdx.x;
    __shared__ int part[1024];
    int local[8];
    int sum = 0;
#pragma unroll
    for (int i = 0; i < 8; ++i) {
        local[i] = counts[(s << 13) + tid * 8 + i];
        sum += local[i];
    }
    part[tid] = sum;
    __syncthreads();
    for (int off = 1; off < 1024; off <<= 1) {
        int v = (tid >= off) ? part[tid - off] : 0;
        __syncthreads();
        part[tid] += v;
        __syncthreads();
    }
    int run = (tid == 0) ? 0 : part[tid - 1];
    const int base9 = s * (NN + 1);
    const int base8 = s << 13;
#pragma unroll
    for (int i = 0; i < 8; ++i) {
        row_ptr[base9 + tid * 8 + i] = run;
        cursor[base8 + tid * 8 + i] = run;
        run += local[i];
    }
    if (tid == 1023) row_ptr[base9 + NN] = run;   // == EE
}

__global__ __launch_bounds__(256) void scatter_kernel(const int* __restrict__ rows,
                                                      const int* __restrict__ cols,
                                                      const float* __restrict__ vals,
                                                      int* __restrict__ cursor,
                                                      int* __restrict__ csr_col,
                                                      float* __restrict__ csr_val) {
    int idx = blockIdx.x * 256 + threadIdx.x;
    if (idx < NS * EE) {
        int s = idx >> 18;
        int r = rows[idx];
        int p = atomicAdd(&cursor[(s << 13) + r], 1);
        csr_col[(s << 18) + p] = cols[idx];
        csr_val[(s << 18) + p] = vals[idx];
    }
}

// ---------------- dense GEMM: Z_m = X0 @ W_m ----------------
// rows r = n*32+b of X0 (A[r][f] = f<64 ? inputs[b][n*64+f] : state[b][n*64+f-64])
// m==0 -> fp32 OUTACC ; m>0 -> bf16 ZS slot
__global__ __launch_bounds__(256) void gemm_kernel(const float* __restrict__ inputs,
                                                   const float* __restrict__ state,
                                                   const float* __restrict__ weight,
                                                   float* __restrict__ outacc,
                                                   unsigned short* __restrict__ zs,
                                                   int mstart) {
    __shared__ float At[64][128];   // [k][r]  32KB
    __shared__ float Wt[64][64];    // [k][o]  16KB
    const int tid = threadIdx.x;
    const int m = mstart + blockIdx.x;
    const int rowbase = blockIdx.y * 128;
    const int tc = tid & 15;        // col group: cols tc*4 .. +3
    const int tr = tid >> 4;        // row group: rows tr*8 .. +7

    float4 acc4[8];
#pragma unroll
    for (int i = 0; i < 8; ++i) acc4[i] = make_float4(0.f, 0.f, 0.f, 0.f);

    for (int kt = 0; kt < 2; ++kt) {
        __syncthreads();
        const float* src = kt ? state : inputs;
        {
            const int rloc = tid & 127;
            const int rg = rowbase + rloc;
            const int n = rg >> 5, b = rg & 31;
            const float* srow = src + (size_t)b * (NN * 64) + n * 64;
#pragma unroll
            for (int i = 0; i < 8; ++i) {
                int k4 = i * 2 + (tid >> 7);
                float4 v = *(const float4*)(srow + k4 * 4);
                At[k4 * 4 + 0][rloc] = v.x;
                At[k4 * 4 + 1][rloc] = v.y;
                At[k4 * 4 + 2][rloc] = v.z;
                At[k4 * 4 + 3][rloc] = v.w;
            }
        }
#pragma unroll
        for (int i = 0; i < 4; ++i) {
            int l4 = i * 256 + tid;           // 1024 float4s
            int k = l4 >> 4, o4 = l4 & 15;
            float4 w = *(const float4*)(weight + ((size_t)(kt * 64 + k) * 5 + m) * 64 + o4 * 4);
            *(float4*)&Wt[k][o4 * 4] = w;
        }
        __syncthreads();
#pragma unroll 4
        for (int k = 0; k < 64; ++k) {
            float4 a0 = *(const float4*)&At[k][tr * 8];
            float4 a1 = *(const float4*)&At[k][tr * 8 + 4];
            float4 w = *(const float4*)&Wt[k][tc * 4];
            float af[8] = {a0.x, a0.y, a0.z, a0.w, a1.x, a1.y, a1.z, a1.w};
#pragma unroll
            for (int i = 0; i < 8; ++i) {
                acc4[i].x += af[i] * w.x;
                acc4[i].y += af[i] * w.y;
                acc4[i].z += af[i] * w.z;
                acc4[i].w += af[i] * w.w;
            }
        }
    }
    const int o = tc * 4;
#pragma unroll
    for (int i = 0; i < 8; ++i) {
        int rg = rowbase + tr * 8 + i;
        int n = rg >> 5, b = rg & 31;
        if (m == 0) {
            *(float4*)&outacc[(size_t)n * 2048 + b * 64 + o] = acc4[i];
        } else {
            int slot = (mstart == 0) ? (m - 1) : (m - 3);
            ushort4 h;
            h.x = f2bf(acc4[i].x); h.y = f2bf(acc4[i].y);
            h.z = f2bf(acc4[i].z); h.w = f2bf(acc4[i].w);
            *(ushort4*)&zs[(size_t)n * 4096 + b * 128 + slot * 64 + o] = h;
        }
    }
}

// ---------------- SpMM 1: OUTACC += A*Z_a ; T = A*Z_b (bf16 operands) ----
// zs rows: 4096 bf16 = 512 uint4 per row. Thread owns 8 consecutive bf16.
__global__ __launch_bounds__(256) void spmm1_kernel(const int* __restrict__ row_ptr,
                                                    const int* __restrict__ csr_col,
                                                    const float* __restrict__ csr_val,
                                                    const unsigned short* __restrict__ zs,
                                                    float* __restrict__ outacc,
                                                    unsigned short* __restrict__ tbuf,
                                                    int s) {
    const int r = blockIdx.y;
    const int d = (blockIdx.x * 256 + threadIdx.x) * 8;   // in [0,4096)
    const int e0 = row_ptr[s * (NN + 1) + r];
    const int e1 = row_ptr[s * (NN + 1) + r + 1];
    const int* cc = csr_col + (s << 18);
    const float* cv = csr_val + (s << 18);
    const uint4* zq = (const uint4*)zs;
    const int dq = d >> 3;
    float acc[8];
#pragma unroll
    for (int i = 0; i < 8; ++i) acc[i] = 0.f;
    for (int e = e0; e < e1; ++e) {
        int c = cc[e];
        float v = cv[e];
        uint4 x = zq[(size_t)c * 512 + dq];
        acc[0] += v * bf_lo(x.x); acc[1] += v * bf_hi(x.x);
        acc[2] += v * bf_lo(x.y); acc[3] += v * bf_hi(x.y);
        acc[4] += v * bf_lo(x.z); acc[5] += v * bf_hi(x.z);
        acc[6] += v * bf_lo(x.w); acc[7] += v * bf_hi(x.w);
    }
    const int f = d & 127, b = d >> 7;
    if (f < 64) {
        float* p = outacc + (size_t)r * 2048 + b * 64 + f;
        float4 o0 = *(float4*)p, o1 = *(float4*)(p + 4);
        o0.x += acc[0]; o0.y += acc[1]; o0.z += acc[2]; o0.w += acc[3];
        o1.x += acc[4]; o1.y += acc[5]; o1.z += acc[6]; o1.w += acc[7];
        *(float4*)p = o0; *(float4*)(p + 4) = o1;
    } else {
        uint4 t;
        t.x = packbf(acc[0], acc[1]); t.y = packbf(acc[2], acc[3]);
        t.z = packbf(acc[4], acc[5]); t.w = packbf(acc[6], acc[7]);
        ((uint4*)tbuf)[((size_t)r * 2048 + b * 64 + (f - 64)) >> 3] = t;
    }
}

// ---------------- SpMM 2: OUTACC += 2*A*T - Z_b (bf16 operands) ----------
// tbuf rows: 2048 bf16 = 256 uint4 per row. One block per row.
__global__ __launch_bounds__(256) void spmm2_kernel(const int* __restrict__ row_ptr,
                                                    const int* __restrict__ csr_col,
                                                    const float* __restrict__ csr_val,
                                                    const unsigned short* __restrict__ tbuf,
                                                    const unsigned short* __restrict__ zs,
                                                    float* __restrict__ outacc,
                                                    int s) {
    const int r = blockIdx.x;
    const int d = threadIdx.x * 8;                        // in [0,2048)
    const int e0 = row_ptr[s * (NN + 1) + r];
    const int e1 = row_ptr[s * (NN + 1) + r + 1];
    const int* cc = csr_col + (s << 18);
    const float* cv = csr_val + (s << 18);
    const uint4* tq = (const uint4*)tbuf;
    const int dq = d >> 3;
    float acc[8];
#pragma unroll
    for (int i = 0; i < 8; ++i) acc[i] = 0.f;
    for (int e = e0; e < e1; ++e) {
        int c = cc[e];
        float v = cv[e];
        uint4 x = tq[(size_t)c * 256 + dq];
        acc[0] += v * bf_lo(x.x); acc[1] += v * bf_hi(x.x);
        acc[2] += v * bf_lo(x.y); acc[3] += v * bf_hi(x.y);
        acc[4] += v * bf_lo(x.z); acc[5] += v * bf_hi(x.z);
        acc[6] += v * bf_lo(x.w); acc[7] += v * bf_hi(x.w);
    }
    const int b = d >> 6, o = d & 63;
    uint4 zb = ((const uint4*)zs)[((size_t)r * 4096 + b * 128 + 64 + o) >> 3];
    float* p = outacc + (size_t)r * 2048 + d;
    float4 o0 = *(float4*)p, o1 = *(float4*)(p + 4);
    o0.x += 2.f * acc[0] - bf_lo(zb.x); o0.y += 2.f * acc[1] - bf_hi(zb.x);
    o0.z += 2.f * acc[2] - bf_lo(zb.y); o0.w += 2.f * acc[3] - bf_hi(zb.y);
    o1.x += 2.f * acc[4] - bf_lo(zb.z); o1.y += 2.f * acc[5] - bf_hi(zb.z);
    o1.z += 2.f * acc[6] - bf_lo(zb.w); o1.w += 2.f * acc[7] - bf_hi(zb.w);
    *(float4*)p = o0; *(float4*)(p + 4) = o1;
}

// ---------------- epilogue: out[b][n*64+o] = OUTACC[n][b][o] + bias[o] ----
__global__ __launch_bounds__(256) void bias_kernel(const float* __restrict__ outacc,
                                                   const float* __restrict__ biases,
                                                   float* __restrict__ out) {
    const int b = blockIdx.y;
    const int n = blockIdx.x * 16 + (threadIdx.x >> 4);
    const int o = (threadIdx.x & 15) * 4;
    float4 v = *(const float4*)(outacc + (size_t)n * 2048 + b * 64 + o);
    float4 bi = *(const float4*)(biases + o);
    v.x += bi.x; v.y += bi.y; v.z += bi.z; v.w += bi.w;
    *(float4*)(out + (size_t)b * (NN * 64) + n * 64 + o) = v;
}

// ---------------- host ----------------
extern "C" void kernel_launch(void* const* d_in, const int* in_sizes, int n_in,
                              void* d_out, int out_size, void* d_ws, size_t ws_size,
                              hipStream_t stream) {
    const float* inputs = (const float*)d_in[0];
    const float* state  = (const float*)d_in[1];
    const int*   rows   = (const int*)d_in[2];
    const int*   cols   = (const int*)d_in[3];
    const float* vals   = (const float*)d_in[4];
    const float* weight = (const float*)d_in[5];
    const float* biases = (const float*)d_in[6];
    float* out = (float*)d_out;

    char* base = (char*)d_ws;
    float*          outacc  = (float*)(base + BOFF_OUTACC);
    unsigned short* zs      = (unsigned short*)(base + BOFF_ZS);
    unsigned short* tbuf    = (unsigned short*)(base + BOFF_T);
    float*          csr_val = (float*)(base + BOFF_CSRVAL);
    int*            csr_col = (int*)(base + BOFF_CSRCOL);
    int*            row_ptr = (int*)(base + BOFF_ROWPTR);
    int*            cursor  = (int*)(base + BOFF_CURSOR);
    int*            counts  = (int*)(base + BOFF_COUNTS);

    // CSR build (both supports)
    hipMemsetAsync(counts, 0, NS * NN * sizeof(int), stream);
    hist_kernel<<<(NS * EE + 255) / 256, 256, 0, stream>>>(rows, counts);
    scan_kernel<<<NS, 1024, 0, stream>>>(counts, row_ptr, cursor);
    scatter_kernel<<<(NS * EE + 255) / 256, 256, 0, stream>>>(rows, cols, vals, cursor,
                                                              csr_col, csr_val);

    for (int s = 0; s < NS; ++s) {
        int mstart = (s == 0) ? 0 : 3;
        int mcount = (s == 0) ? 3 : 2;   // pass 0 also produces the m=0 (identity) term
        gemm_kernel<<<dim3(mcount, NB / 128), 256, 0, stream>>>(inputs, state, weight,
                                                                outacc, zs, mstart);
        spmm1_kernel<<<dim3(2, NN), 256, 0, stream>>>(row_ptr, csr_col, csr_val, zs,
                                                      outacc, tbuf, s);
        spmm2_kernel<<<NN, 256, 0, stream>>>(row_ptr, csr_col, csr_val, tbuf,
                                             zs, outacc, s);
    }

    bias_kernel<<<dim3(NN / 16, BB), 256, 0, stream>>>(outacc, biases, out);
}

// Round 7
// 1075.454 us; speedup vs baseline: 1.2674x; 1.2674x over previous
//
#include <hip/hip_runtime.h>

// ---------------- problem constants ----------------
#define NN      8192            // nodes
#define BB      32              // batch
#define EE      262144          // edges per support (2^18)
#define NB      (NN*BB)         // 262144 gemm rows
#define NS      2               // supports

// ---------------- workspace layout (byte offsets) ----------------
// outacc f32  [NN][BB][64]  64 MB
// za     bf16 [NN][2048]    32 MB  (per-support, reused; V overwrites in place)
// zb     bf16 [NN][2048]    32 MB  (per-support, reused)
#define BOFF_OUTACC 0
#define BOFF_ZA     67108864
#define BOFF_ZB     100663296
#define BOFF_CSRVAL 134217728                    // f32  NS*EE
#define BOFF_CSRCOL (BOFF_CSRVAL + 2097152)      // int  NS*EE
#define BOFF_ROWPTR (BOFF_CSRCOL + 2097152)      // int  NS*(NN+1)
#define BOFF_CURSOR (BOFF_ROWPTR + 65544)        // int  NS*NN
#define BOFF_COUNTS (BOFF_CURSOR + 65536)        // int  NS*NN
// end ~132.2 MB

// ---------------- bf16 helpers (RNE) ----------------
__device__ __forceinline__ unsigned short f2bf(float f) {
    union { float f; unsigned u; } v; v.f = f;
    unsigned r = v.u + 0x7fffu + ((v.u >> 16) & 1u);
    return (unsigned short)(r >> 16);
}
__device__ __forceinline__ float bf_lo(unsigned u) {
    union { unsigned u; float f; } v; v.u = u << 16; return v.f;
}
__device__ __forceinline__ float bf_hi(unsigned u) {
    union { unsigned u; float f; } v; v.u = u & 0xffff0000u; return v.f;
}
__device__ __forceinline__ unsigned packbf(float lo, float hi) {
    return (unsigned)f2bf(lo) | ((unsigned)f2bf(hi) << 16);
}

// ---------------- CSR build ----------------
__global__ __launch_bounds__(256) void hist_kernel(const int* __restrict__ rows,
                                                   int* __restrict__ counts) {
    int idx = blockIdx.x * 256 + threadIdx.x;
    if (idx < NS * EE) {
        int s = idx >> 18;
        int r = rows[idx];
        atomicAdd(&counts[(s << 13) + r], 1);
    }
}

__global__ __launch_bounds__(1024) void scan_kernel(const int* __restrict__ counts,
                                                    int* __restrict__ row_ptr,
                                                    int* __restrict__ cursor) {
    const int s = blockIdx.x;
    const int tid = threadIdx.x;
    __shared__ int part[1024];
    int local[8];
    int sum = 0;
#pragma unroll
    for (int i = 0; i < 8; ++i) {
        local[i] = counts[(s << 13) + tid * 8 + i];
        sum += local[i];
    }
    part[tid] = sum;
    __syncthreads();
    for (int off = 1; off < 1024; off <<= 1) {
        int v = (tid >= off) ? part[tid - off] : 0;
        __syncthreads();
        part[tid] += v;
        __syncthreads();
    }
    int run = (tid == 0) ? 0 : part[tid - 1];
    const int base9 = s * (NN + 1);
    const int base8 = s << 13;
#pragma unroll
    for (int i = 0; i < 8; ++i) {
        row_ptr[base9 + tid * 8 + i] = run;
        cursor[base8 + tid * 8 + i] = run;
        run += local[i];
    }
    if (tid == 1023) row_ptr[base9 + NN] = run;   // == EE
}

__global__ __launch_bounds__(256) void scatter_kernel(const int* __restrict__ rows,
                                                      const int* __restrict__ cols,
                                                      const float* __restrict__ vals,
                                                      int* __restrict__ cursor,
                                                      int* __restrict__ csr_col,
                                                      float* __restrict__ csr_val) {
    int idx = blockIdx.x * 256 + threadIdx.x;
    if (idx < NS * EE) {
        int s = idx >> 18;
        int r = rows[idx];
        int p = atomicAdd(&cursor[(s << 13) + r], 1);
        csr_col[(s << 18) + p] = cols[idx];
        csr_val[(s << 18) + p] = vals[idx];
    }
}

// ---------------- dense GEMM: Z_m = X0 @ W_m ----------------
// rows r = n*32+b of X0 (A[r][f] = f<64 ? inputs[b][n*64+f] : state[b][n*64+f-64])
// m==0 -> fp32 OUTACC ; m==1/3 -> bf16 za ; m==2/4 -> bf16 zb
__global__ __launch_bounds__(256) void gemm_kernel(const float* __restrict__ inputs,
                                                   const float* __restrict__ state,
                                                   const float* __restrict__ weight,
                                                   float* __restrict__ outacc,
                                                   unsigned short* __restrict__ za,
                                                   unsigned short* __restrict__ zb,
                                                   int mstart) {
    __shared__ float At[64][128];   // [k][r]  32KB
    __shared__ float Wt[64][64];    // [k][o]  16KB
    const int tid = threadIdx.x;
    const int m = mstart + blockIdx.x;
    const int rowbase = blockIdx.y * 128;
    const int tc = tid & 15;        // col group: cols tc*4 .. +3
    const int tr = tid >> 4;        // row group: rows tr*8 .. +7

    float4 acc4[8];
#pragma unroll
    for (int i = 0; i < 8; ++i) acc4[i] = make_float4(0.f, 0.f, 0.f, 0.f);

    for (int kt = 0; kt < 2; ++kt) {
        __syncthreads();
        const float* src = kt ? state : inputs;
        {
            const int rloc = tid & 127;
            const int rg = rowbase + rloc;
            const int n = rg >> 5, b = rg & 31;
            const float* srow = src + (size_t)b * (NN * 64) + n * 64;
#pragma unroll
            for (int i = 0; i < 8; ++i) {
                int k4 = i * 2 + (tid >> 7);
                float4 v = *(const float4*)(srow + k4 * 4);
                At[k4 * 4 + 0][rloc] = v.x;
                At[k4 * 4 + 1][rloc] = v.y;
                At[k4 * 4 + 2][rloc] = v.z;
                At[k4 * 4 + 3][rloc] = v.w;
            }
        }
#pragma unroll
        for (int i = 0; i < 4; ++i) {
            int l4 = i * 256 + tid;           // 1024 float4s
            int k = l4 >> 4, o4 = l4 & 15;
            float4 w = *(const float4*)(weight + ((size_t)(kt * 64 + k) * 5 + m) * 64 + o4 * 4);
            *(float4*)&Wt[k][o4 * 4] = w;
        }
        __syncthreads();
#pragma unroll 4
        for (int k = 0; k < 64; ++k) {
            float4 a0 = *(const float4*)&At[k][tr * 8];
            float4 a1 = *(const float4*)&At[k][tr * 8 + 4];
            float4 w = *(const float4*)&Wt[k][tc * 4];
            float af[8] = {a0.x, a0.y, a0.z, a0.w, a1.x, a1.y, a1.z, a1.w};
#pragma unroll
            for (int i = 0; i < 8; ++i) {
                acc4[i].x += af[i] * w.x;
                acc4[i].y += af[i] * w.y;
                acc4[i].z += af[i] * w.z;
                acc4[i].w += af[i] * w.w;
            }
        }
    }
    const int o = tc * 4;
#pragma unroll
    for (int i = 0; i < 8; ++i) {
        int rg = rowbase + tr * 8 + i;
        int n = rg >> 5, b = rg & 31;
        if (m == 0) {
            *(float4*)&outacc[(size_t)n * 2048 + b * 64 + o] = acc4[i];
        } else {
            unsigned short* dst = (m == 1 || m == 3) ? za : zb;
            ushort4 h;
            h.x = f2bf(acc4[i].x); h.y = f2bf(acc4[i].y);
            h.z = f2bf(acc4[i].z); h.w = f2bf(acc4[i].w);
            *(ushort4*)&dst[(size_t)n * 2048 + b * 64 + o] = h;
        }
    }
}

// ---------------- SpMM U: V = Z_a + 2*(A @ Z_b), in place into za ----------
// one block per row r; thread owns 8 consecutive bf16 (row = 256 uint4)
__global__ __launch_bounds__(256) void spmmU_kernel(const int* __restrict__ row_ptr,
                                                    const int* __restrict__ csr_col,
                                                    const float* __restrict__ csr_val,
                                                    unsigned short* __restrict__ za,
                                                    const unsigned short* __restrict__ zb,
                                                    int s) {
    const int r = blockIdx.x;
    const int tid = threadIdx.x;
    const int e0 = row_ptr[s * (NN + 1) + r];
    const int e1 = row_ptr[s * (NN + 1) + r + 1];
    const int* cc = csr_col + (s << 18);
    const float* cv = csr_val + (s << 18);
    const uint4* zbq = (const uint4*)zb;
    float acc[8];
#pragma unroll
    for (int i = 0; i < 8; ++i) acc[i] = 0.f;
    for (int e = e0; e < e1; ++e) {
        int c = cc[e];
        float v = cv[e];
        uint4 x = zbq[(size_t)c * 256 + tid];
        acc[0] += v * bf_lo(x.x); acc[1] += v * bf_hi(x.x);
        acc[2] += v * bf_lo(x.y); acc[3] += v * bf_hi(x.y);
        acc[4] += v * bf_lo(x.z); acc[5] += v * bf_hi(x.z);
        acc[6] += v * bf_lo(x.w); acc[7] += v * bf_hi(x.w);
    }
    // V[r] = za[r] + 2*acc  (in place; this block is the only reader/writer of row r)
    uint4* zaq = (uint4*)za;
    uint4 a = zaq[(size_t)r * 256 + tid];
    uint4 outv;
    outv.x = packbf(bf_lo(a.x) + 2.f * acc[0], bf_hi(a.x) + 2.f * acc[1]);
    outv.y = packbf(bf_lo(a.y) + 2.f * acc[2], bf_hi(a.y) + 2.f * acc[3]);
    outv.z = packbf(bf_lo(a.z) + 2.f * acc[4], bf_hi(a.z) + 2.f * acc[5]);
    outv.w = packbf(bf_lo(a.w) + 2.f * acc[6], bf_hi(a.w) + 2.f * acc[7]);
    zaq[(size_t)r * 256 + tid] = outv;
}

// ---------------- SpMM V: OUTACC += (A @ V) - Z_b ------------------------
__global__ __launch_bounds__(256) void spmmV_kernel(const int* __restrict__ row_ptr,
                                                    const int* __restrict__ csr_col,
                                                    const float* __restrict__ csr_val,
                                                    const unsigned short* __restrict__ vbuf,
                                                    const unsigned short* __restrict__ zb,
                                                    float* __restrict__ outacc,
                                                    int s) {
    const int r = blockIdx.x;
    const int tid = threadIdx.x;
    const int e0 = row_ptr[s * (NN + 1) + r];
    const int e1 = row_ptr[s * (NN + 1) + r + 1];
    const int* cc = csr_col + (s << 18);
    const float* cv = csr_val + (s << 18);
    const uint4* vq = (const uint4*)vbuf;
    float acc[8];
#pragma unroll
    for (int i = 0; i < 8; ++i) acc[i] = 0.f;
    for (int e = e0; e < e1; ++e) {
        int c = cc[e];
        float v = cv[e];
        uint4 x = vq[(size_t)c * 256 + tid];
        acc[0] += v * bf_lo(x.x); acc[1] += v * bf_hi(x.x);
        acc[2] += v * bf_lo(x.y); acc[3] += v * bf_hi(x.y);
        acc[4] += v * bf_lo(x.z); acc[5] += v * bf_hi(x.z);
        acc[6] += v * bf_lo(x.w); acc[7] += v * bf_hi(x.w);
    }
    uint4 t = ((const uint4*)zb)[(size_t)r * 256 + tid];
    float* p = outacc + (size_t)r * 2048 + tid * 8;
    float4 o0 = *(float4*)p, o1 = *(float4*)(p + 4);
    o0.x += acc[0] - bf_lo(t.x); o0.y += acc[1] - bf_hi(t.x);
    o0.z += acc[2] - bf_lo(t.y); o0.w += acc[3] - bf_hi(t.y);
    o1.x += acc[4] - bf_lo(t.z); o1.y += acc[5] - bf_hi(t.z);
    o1.z += acc[6] - bf_lo(t.w); o1.w += acc[7] - bf_hi(t.w);
    *(float4*)p = o0; *(float4*)(p + 4) = o1;
}

// ---------------- epilogue: out[b][n*64+o] = OUTACC[n][b][o] + bias[o] ----
__global__ __launch_bounds__(256) void bias_kernel(const float* __restrict__ outacc,
                                                   const float* __restrict__ biases,
                                                   float* __restrict__ out) {
    const int b = blockIdx.y;
    const int n = blockIdx.x * 16 + (threadIdx.x >> 4);
    const int o = (threadIdx.x & 15) * 4;
    float4 v = *(const float4*)(outacc + (size_t)n * 2048 + b * 64 + o);
    float4 bi = *(const float4*)(biases + o);
    v.x += bi.x; v.y += bi.y; v.z += bi.z; v.w += bi.w;
    *(float4*)(out + (size_t)b * (NN * 64) + n * 64 + o) = v;
}

// ---------------- host ----------------
extern "C" void kernel_launch(void* const* d_in, const int* in_sizes, int n_in,
                              void* d_out, int out_size, void* d_ws, size_t ws_size,
                              hipStream_t stream) {
    const float* inputs = (const float*)d_in[0];
    const float* state  = (const float*)d_in[1];
    const int*   rows   = (const int*)d_in[2];
    const int*   cols   = (const int*)d_in[3];
    const float* vals   = (const float*)d_in[4];
    const float* weight = (const float*)d_in[5];
    const float* biases = (const float*)d_in[6];
    float* out = (float*)d_out;

    char* base = (char*)d_ws;
    float*          outacc  = (float*)(base + BOFF_OUTACC);
    unsigned short* za      = (unsigned short*)(base + BOFF_ZA);
    unsigned short* zb      = (unsigned short*)(base + BOFF_ZB);
    float*          csr_val = (float*)(base + BOFF_CSRVAL);
    int*            csr_col = (int*)(base + BOFF_CSRCOL);
    int*            row_ptr = (int*)(base + BOFF_ROWPTR);
    int*            cursor  = (int*)(base + BOFF_CURSOR);
    int*            counts  = (int*)(base + BOFF_COUNTS);

    // CSR build (both supports)
    hipMemsetAsync(counts, 0, NS * NN * sizeof(int), stream);
    hist_kernel<<<(NS * EE + 255) / 256, 256, 0, stream>>>(rows, counts);
    scan_kernel<<<NS, 1024, 0, stream>>>(counts, row_ptr, cursor);
    scatter_kernel<<<(NS * EE + 255) / 256, 256, 0, stream>>>(rows, cols, vals, cursor,
                                                              csr_col, csr_val);

    for (int s = 0; s < NS; ++s) {
        int mstart = (s == 0) ? 0 : 3;
        int mcount = (s == 0) ? 3 : 2;   // s=0 also produces the m=0 (identity) term
        gemm_kernel<<<dim3(mcount, NB / 128), 256, 0, stream>>>(inputs, state, weight,
                                                                outacc, za, zb, mstart);
        spmmU_kernel<<<NN, 256, 0, stream>>>(row_ptr, csr_col, csr_val, za, zb, s);
        spmmV_kernel<<<NN, 256, 0, stream>>>(row_ptr, csr_col, csr_val, za, zb,
                                             outacc, s);
    }

    bias_kernel<<<dim3(NN / 16, BB), 256, 0, stream>>>(outacc, biases, out);
}